// Round 1
// baseline (545.403 us; speedup 1.0000x reference)
//
#include <hip/hip_runtime.h>
#include <cstdint>

#define AS1 __attribute__((address_space(1)))
#define AS3 __attribute__((address_space(3)))

typedef _Float16 half8 __attribute__((ext_vector_type(8)));
typedef _Float16 half4_t __attribute__((ext_vector_type(4)));
typedef float v4f __attribute__((ext_vector_type(4)));

__device__ __forceinline__ void async_ld16(const void* g, void* l) {
  // direct global->LDS DMA, 16B per lane; LDS dest = wave-uniform base + lane*16
  __builtin_amdgcn_global_load_lds((const AS1 uint32_t*)g, (AS3 uint32_t*)l, 16, 0, 0);
}

// T5 relative-position bucket for delta = k - q (bidirectional, 32 buckets, max_dist 128).
// Exact-boundary cases (n = 8,16,32,64) computed in integer arithmetic; n>=91 clamps to 15;
// remaining float path has >=0.015 margin in value space vs ~1e-6 fp32 error.
__device__ __forceinline__ int t5_bucket(int delta) {
  int n = -delta;  // n = q - k
  int ret = 0;
  if (n < 0) { ret = 16; n = -n; }
  if (n < 8) return n + ret;
  if (n >= 91) return 15 + ret;
  if ((n & (n - 1)) == 0) {  // n = 8,16,32,64 : val = 8 + 2*log2(n) - 6 exactly
    int l = 31 - __clz(n);
    int v = 2 + 2 * l;
    return (v > 15 ? 15 : v) + ret;
  }
  int v = 8 + (int)(logf((float)n * 0.125f) * (8.0f / logf(16.0f)));
  return (v > 15 ? 15 : v) + ret;
}

// ---------------- fp32 -> fp16 convert (hidden states) ----------------
__global__ void k_cvt(const float* __restrict__ src, _Float16* __restrict__ dst) {
  int t = blockIdx.x * 256 + threadIdx.x;
  float4 f = ((const float4*)src)[t];
  half4_t h = {(_Float16)f.x, (_Float16)f.y, (_Float16)f.z, (_Float16)f.w};
  ((half4_t*)dst)[t] = h;
}

// ---------------- fp32 1024x1024 transpose -> fp16 ----------------
__global__ void k_wt(const float* __restrict__ src, _Float16* __restrict__ dst) {
  __shared__ float tile[32][33];
  int tx = threadIdx.x, ty = threadIdx.y;
  int bx = blockIdx.x * 32, by = blockIdx.y * 32;
#pragma unroll
  for (int i = 0; i < 32; i += 8)
    tile[ty + i][tx] = src[(size_t)(by + ty + i) * 1024 + bx + tx];
  __syncthreads();
#pragma unroll
  for (int i = 0; i < 32; i += 8)
    dst[(size_t)(bx + ty + i) * 1024 + by + tx] = (_Float16)tile[tx][ty + i];
}

// ---------------- position bias: out[h][q][k] = rel_emb[bucket(k-q)][h] ----------------
__global__ void k_bias(const float* __restrict__ rel, float* __restrict__ outb) {
  __shared__ float tbl[512];
  int tid = threadIdx.x;
  tbl[tid] = rel[tid];
  tbl[tid + 256] = rel[tid + 256];
  __syncthreads();
  unsigned t = blockIdx.x * 256 + tid;
  int k4 = t & 511;
  int q = (t >> 9) & 2047;
  int h = t >> 20;
  int kb = k4 * 4;
  float4 v;
  v.x = tbl[t5_bucket(kb + 0 - q) * 16 + h];
  v.y = tbl[t5_bucket(kb + 1 - q) * 16 + h];
  v.z = tbl[t5_bucket(kb + 2 - q) * 16 + h];
  v.w = tbl[t5_bucket(kb + 3 - q) * 16 + h];
  ((float4*)outb)[((size_t)h * 2048 + q) * 512 + k4] = v;
}

// ---------------- fp16 MFMA GEMM: C[M,N] = A[M,K] * B[K,N], B given transposed (BT[N,K]) ----
// 128x128 tile, BK=32, 256 threads (2x2 waves of 64x64), global_load_lds staging (m97 pattern).
template <bool F16OUT>
__global__ __launch_bounds__(256, 2) void k_gemm(const _Float16* __restrict__ A,
                                                 const _Float16* __restrict__ BT,
                                                 void* __restrict__ Cv, int K, int ldc) {
  __shared__ __align__(16) _Float16 As[128 * 32];
  __shared__ __align__(16) _Float16 Bs[128 * 32];
  const int tid = threadIdx.x;
  const int wave = tid >> 6, lane = tid & 63;
  const int l15 = lane & 15, quad = lane >> 4;
  const int m0 = blockIdx.y * 128, n0 = blockIdx.x * 128;
  const int wm = (wave >> 1) * 64, wn = (wave & 1) * 64;
  const int r0 = tid >> 2;         // staging row (it=0): 0..63
  const int c0 = (tid & 3) * 8;    // staging col offset in halves
  v4f acc[4][4] = {};
  for (int k0 = 0; k0 < K; k0 += 32) {
    __syncthreads();
    async_ld16(A + (size_t)(m0 + r0) * K + k0 + c0, (char*)As + (size_t)(wave * 64) * 16);
    async_ld16(A + (size_t)(m0 + 64 + r0) * K + k0 + c0,
               (char*)As + (size_t)(256 + wave * 64) * 16);
    async_ld16(BT + (size_t)(n0 + r0) * K + k0 + c0, (char*)Bs + (size_t)(wave * 64) * 16);
    async_ld16(BT + (size_t)(n0 + 64 + r0) * K + k0 + c0,
               (char*)Bs + (size_t)(256 + wave * 64) * 16);
    __syncthreads();
    half8 af[4], bf[4];
#pragma unroll
    for (int mt = 0; mt < 4; ++mt)
      af[mt] = *(const half8*)(As + (wm + mt * 16 + l15) * 32 + quad * 8);
#pragma unroll
    for (int nt = 0; nt < 4; ++nt)
      bf[nt] = *(const half8*)(Bs + (wn + nt * 16 + l15) * 32 + quad * 8);
#pragma unroll
    for (int mt = 0; mt < 4; ++mt)
#pragma unroll
      for (int nt = 0; nt < 4; ++nt)
        acc[mt][nt] = __builtin_amdgcn_mfma_f32_16x16x32_f16(af[mt], bf[nt], acc[mt][nt], 0, 0, 0);
  }
#pragma unroll
  for (int mt = 0; mt < 4; ++mt)
#pragma unroll
    for (int nt = 0; nt < 4; ++nt)
#pragma unroll
      for (int r = 0; r < 4; ++r) {
        int row = m0 + wm + mt * 16 + quad * 4 + r;  // C layout: row = quad*4+reg
        int col = n0 + wn + nt * 16 + l15;           // col = lane&15
        if (F16OUT)
          ((_Float16*)Cv)[(size_t)row * ldc + col] = (_Float16)acc[mt][nt][r];
        else
          ((float*)Cv)[(size_t)row * ldc + col] = acc[mt][nt][r];
      }
}

// ---------------- fused flash attention with T5 bias ----------------
// grid (S/64, H, B); 256 threads = 4 waves; wave w owns q-rows qb*64 + w*16 .. +15.
__global__ __launch_bounds__(256, 2) void k_attn(const _Float16* __restrict__ qkv,
                                                 const float* __restrict__ mask,
                                                 const float* __restrict__ rel,
                                                 _Float16* __restrict__ ctx) {
  __shared__ __align__(16) _Float16 Ks[64 * 72];       // K tile [kv][d], pad 8
  __shared__ __align__(16) _Float16 VT[64 * 72];       // V tile transposed [d][kv], pad 8
  __shared__ __align__(16) _Float16 Psh[4][16 * 72];   // per-wave P tile [q][kv], pad 8
  __shared__ float btab[4095];                         // bias per delta for this head
  __shared__ float maskS[64];
  const int S = 2048, LD = 3072;
  const int tid = threadIdx.x, wave = tid >> 6, lane = tid & 63;
  const int l15 = lane & 15, quad = lane >> 4;
  const int q0 = blockIdx.x * 64, h = blockIdx.y, b = blockIdx.z;

  for (int j = tid; j < 4095; j += 256)
    btab[j] = rel[t5_bucket(j - 2047) * 16 + h];

  // Q fragments (A-layout: m = lane&15, k = quad*8+j), held in registers for whole kernel
  half8 aq[2];
  {
    const _Float16* qp = qkv + (size_t)(b * S + q0 + wave * 16 + l15) * LD + h * 64;
    aq[0] = *(const half8*)(qp + quad * 8);
    aq[1] = *(const half8*)(qp + 32 + quad * 8);
  }
  v4f o[4] = {};
  float mrun[4] = {-1e30f, -1e30f, -1e30f, -1e30f};
  float lrun[4] = {0.f, 0.f, 0.f, 0.f};

  const int sr = tid >> 3, sc8 = (tid & 7) * 8;

  for (int kv0 = 0; kv0 < S; kv0 += 64) {
    __syncthreads();
    // stage K rows (row-major, padded)
#pragma unroll
    for (int it = 0; it < 2; ++it) {
      int row = it * 32 + sr;
      const _Float16* kp = qkv + (size_t)(b * S + kv0 + row) * LD + 1024 + h * 64 + sc8;
      *(half8*)(Ks + row * 72 + sc8) = *(const half8*)kp;
    }
    // stage V transposed, d-major so LDS writes are balanced b128s:
    // lane = d, wave = kv-quarter; 16 scalar global loads (coalesced across lanes), 2 b128 writes
    {
      int d = lane;
      const _Float16* vp = qkv + (size_t)(b * S + kv0 + wave * 16) * LD + 2048 + h * 64 + d;
      half8 v0h, v1h;
#pragma unroll
      for (int e = 0; e < 8; ++e) v0h[e] = vp[(size_t)e * LD];
#pragma unroll
      for (int e = 0; e < 8; ++e) v1h[e] = vp[(size_t)(8 + e) * LD];
      *(half8*)(VT + d * 72 + wave * 16) = v0h;
      *(half8*)(VT + d * 72 + wave * 16 + 8) = v1h;
    }
    if (tid < 64) maskS[tid] = mask[b * S + kv0 + tid];
    __syncthreads();

    // S = Q K^T  (B-fragment from Ks rows: n = lane&15 -> kv, k = quad*8+j -> d)
    v4f sc[4] = {};
#pragma unroll
    for (int c = 0; c < 2; ++c)
#pragma unroll
      for (int nt = 0; nt < 4; ++nt) {
        half8 bk = *(const half8*)(Ks + (nt * 16 + l15) * 72 + c * 32 + quad * 8);
        sc[nt] = __builtin_amdgcn_mfma_f32_16x16x32_f16(aq[c], bk, sc[nt], 0, 0, 0);
      }
    // + position bias + mask (C layout: row = quad*4+r, col = lane&15)
    const int qrow = q0 + wave * 16 + quad * 4;
#pragma unroll
    for (int nt = 0; nt < 4; ++nt) {
      int col = kv0 + nt * 16 + l15;
      float mk = maskS[nt * 16 + l15];
#pragma unroll
      for (int r = 0; r < 4; ++r) sc[nt][r] += btab[col - (qrow + r) + 2047] + mk;
    }
    // online softmax; rows of a 16x16 C tile live in one quad (16 lanes) -> xor 1,2,4,8
#pragma unroll
    for (int r = 0; r < 4; ++r) {
      float mx = fmaxf(fmaxf(sc[0][r], sc[1][r]), fmaxf(sc[2][r], sc[3][r]));
#pragma unroll
      for (int off = 1; off < 16; off <<= 1) mx = fmaxf(mx, __shfl_xor(mx, off, 64));
      float mnew = fmaxf(mrun[r], mx);
      float alpha = __expf(mrun[r] - mnew);
      float rsum = 0.f;
#pragma unroll
      for (int nt = 0; nt < 4; ++nt) {
        float p = __expf(sc[nt][r] - mnew);
        sc[nt][r] = p;
        rsum += p;
      }
#pragma unroll
      for (int off = 1; off < 16; off <<= 1) rsum += __shfl_xor(rsum, off, 64);
      mrun[r] = mnew;
      lrun[r] = lrun[r] * alpha + rsum;
      o[0][r] *= alpha; o[1][r] *= alpha; o[2][r] *= alpha; o[3][r] *= alpha;
    }
    // P: C-layout -> LDS -> A-layout (verified m120 pattern)
    _Float16* Pw = &Psh[wave][0];
#pragma unroll
    for (int nt = 0; nt < 4; ++nt)
#pragma unroll
      for (int r = 0; r < 4; ++r)
        Pw[(quad * 4 + r) * 72 + nt * 16 + l15] = (_Float16)sc[nt][r];
    __syncthreads();
    // O += P V   (B-fragment from VT rows: n = lane&15 -> d, k = quad*8+j -> kv)
#pragma unroll
    for (int c = 0; c < 2; ++c) {
      half8 ap = *(const half8*)(Pw + l15 * 72 + c * 32 + quad * 8);
#pragma unroll
      for (int dt = 0; dt < 4; ++dt) {
        half8 bv = *(const half8*)(VT + (dt * 16 + l15) * 72 + c * 32 + quad * 8);
        o[dt] = __builtin_amdgcn_mfma_f32_16x16x32_f16(ap, bv, o[dt], 0, 0, 0);
      }
    }
  }
  // epilogue: normalize and store context [B,S,H*64] fp16
#pragma unroll
  for (int dt = 0; dt < 4; ++dt)
#pragma unroll
    for (int r = 0; r < 4; ++r) {
      float val = o[dt][r] / lrun[r];
      ctx[(size_t)(b * S + q0 + wave * 16 + quad * 4 + r) * 1024 + h * 64 + dt * 16 + l15] =
          (_Float16)val;
    }
}

extern "C" void kernel_launch(void* const* d_in, const int* in_sizes, int n_in,
                              void* d_out, int out_size, void* d_ws, size_t ws_size,
                              hipStream_t stream) {
  const float* hs = (const float*)d_in[0];
  const float* mask = (const float*)d_in[1];
  const float* Wq = (const float*)d_in[2];
  const float* Wk = (const float*)d_in[3];
  const float* Wv = (const float*)d_in[4];
  const float* Wo = (const float*)d_in[5];
  const float* rel = (const float*)d_in[6];
  float* out = (float*)d_out;

  // workspace layout (48 MB total)
  char* ws = (char*)d_ws;
  _Float16* hsF = (_Float16*)(ws);                  // [4096,1024]      8 MB
  _Float16* wqkvT = (_Float16*)(ws + (8u << 20));   // [3072,1024]      6 MB (Wq^T|Wk^T|Wv^T)
  _Float16* woT = (_Float16*)(ws + (14u << 20));    // [1024,1024]      2 MB
  _Float16* qkv = (_Float16*)(ws + (16u << 20));    // [4096,3072]     24 MB
  _Float16* ctx = (_Float16*)(ws + (40u << 20));    // [4096,1024]      8 MB

  k_cvt<<<4096, 256, 0, stream>>>(hs, hsF);
  k_wt<<<dim3(32, 32), dim3(32, 8), 0, stream>>>(Wq, wqkvT);
  k_wt<<<dim3(32, 32), dim3(32, 8), 0, stream>>>(Wk, wqkvT + (1u << 20));
  k_wt<<<dim3(32, 32), dim3(32, 8), 0, stream>>>(Wv, wqkvT + (2u << 20));
  k_wt<<<dim3(32, 32), dim3(32, 8), 0, stream>>>(Wo, woT);

  // QKV projection: [4096,1024] x [1024,3072]
  k_gemm<true><<<dim3(24, 32), 256, 0, stream>>>(hsF, wqkvT, qkv, 1024, 3072);
  // position bias output (268 MB, memory-bound)
  k_bias<<<65536, 256, 0, stream>>>(rel, out + 4194304);
  // fused attention
  k_attn<<<dim3(32, 16, 2), 256, 0, stream>>>(qkv, mask, rel, ctx);
  // output projection: [4096,1024] x [1024,1024] -> fp32 out
  k_gemm<false><<<dim3(8, 32), 256, 0, stream>>>(ctx, woT, out, 1024, 1024);
}

// Round 2
// 460.918 us; speedup vs baseline: 1.1833x; 1.1833x over previous
//
#include <hip/hip_runtime.h>
#include <cstdint>

#define AS1 __attribute__((address_space(1)))
#define AS3 __attribute__((address_space(3)))

typedef _Float16 half8 __attribute__((ext_vector_type(8)));
typedef _Float16 half4_t __attribute__((ext_vector_type(4)));
typedef float v4f __attribute__((ext_vector_type(4)));

__device__ __forceinline__ void async_ld16(const void* g, void* l) {
  __builtin_amdgcn_global_load_lds((const AS1 uint32_t*)g, (AS3 uint32_t*)l, 16, 0, 0);
}

// T5 relative-position bucket for delta = k - q (bidirectional, 32 buckets, max_dist 128).
// Exact-boundary cases (n = 8,16,32,64) in integer arithmetic; n>=91 clamps; float path
// has >=0.015 margin in value space vs ~1e-6 fp32 error.
__device__ __forceinline__ int t5_bucket(int delta) {
  int n = -delta;  // n = q - k
  int ret = 0;
  if (n < 0) { ret = 16; n = -n; }
  if (n < 8) return n + ret;
  if (n >= 91) return 15 + ret;
  if ((n & (n - 1)) == 0) {
    int l = 31 - __clz(n);
    int v = 2 + 2 * l;
    return (v > 15 ? 15 : v) + ret;
  }
  int v = 8 + (int)(logf((float)n * 0.125f) * (8.0f / logf(16.0f)));
  return (v > 15 ? 15 : v) + ret;
}

// ---------------- fp32 -> fp16 convert (hidden states) ----------------
__global__ void k_cvt(const float* __restrict__ src, _Float16* __restrict__ dst) {
  int t = blockIdx.x * 256 + threadIdx.x;
  float4 f = ((const float4*)src)[t];
  half4_t h = {(_Float16)f.x, (_Float16)f.y, (_Float16)f.z, (_Float16)f.w};
  ((half4_t*)dst)[t] = h;
}

// ---------------- fp32 1024x1024 transpose -> fp16 ----------------
__global__ void k_wt(const float* __restrict__ src, _Float16* __restrict__ dst) {
  __shared__ float tile[32][33];
  int tx = threadIdx.x, ty = threadIdx.y;
  int bx = blockIdx.x * 32, by = blockIdx.y * 32;
#pragma unroll
  for (int i = 0; i < 32; i += 8)
    tile[ty + i][tx] = src[(size_t)(by + ty + i) * 1024 + bx + tx];
  __syncthreads();
#pragma unroll
  for (int i = 0; i < 32; i += 8)
    dst[(size_t)(bx + ty + i) * 1024 + by + tx] = (_Float16)tile[tx][ty + i];
}

// ---------------- V transpose: qkv V-part [s][h*64+d] -> vT[(b,h,d)][s] ----------------
__global__ void k_vt(const _Float16* __restrict__ qkv, _Float16* __restrict__ vT) {
  __shared__ float tile[64 * 73];  // LD=73 floats: conflict-free column gather
  const int t = threadIdx.x;
  const int s0 = blockIdx.x * 64, h = blockIdx.y, b = blockIdx.z;
  const int r = t >> 2, c = (t & 3) * 16;
  const _Float16* src = qkv + (size_t)(b * 2048 + s0 + r) * 3072 + 2048 + h * 64 + c;
  half8 a0 = *(const half8*)src;
  half8 a1 = *(const half8*)(src + 8);
#pragma unroll
  for (int e = 0; e < 8; ++e) tile[r * 73 + c + e] = (float)a0[e];
#pragma unroll
  for (int e = 0; e < 8; ++e) tile[r * 73 + c + 8 + e] = (float)a1[e];
  __syncthreads();
  half8 w0, w1;
#pragma unroll
  for (int e = 0; e < 8; ++e) w0[e] = (_Float16)tile[(c + e) * 73 + r];
#pragma unroll
  for (int e = 0; e < 8; ++e) w1[e] = (_Float16)tile[(c + 8 + e) * 73 + r];
  _Float16* dst = vT + ((size_t)((b * 16 + h) * 64 + r)) * 2048 + s0 + c;
  *(half8*)dst = w0;
  *(half8*)(dst + 8) = w1;
}

// ---------------- position bias: out[h][q][k] = rel_emb[bucket(k-q)][h] ----------------
__global__ void k_bias(const float* __restrict__ rel, float* __restrict__ outb) {
  __shared__ float tbl[512];
  int tid = threadIdx.x;
  tbl[tid] = rel[tid];
  tbl[tid + 256] = rel[tid + 256];
  __syncthreads();
  unsigned t = blockIdx.x * 256 + tid;
  int k4 = t & 511;
  int q = (t >> 9) & 2047;
  int h = t >> 20;
  int kb = k4 * 4;
  float4 v;
  if (kb - q >= 91) {  // all 4 deltas >= 91 -> bucket 31
    float c = tbl[31 * 16 + h];
    v = make_float4(c, c, c, c);
  } else if (q - kb - 3 >= 91) {  // all 4 -> bucket 15
    float c = tbl[15 * 16 + h];
    v = make_float4(c, c, c, c);
  } else {
    v.x = tbl[t5_bucket(kb + 0 - q) * 16 + h];
    v.y = tbl[t5_bucket(kb + 1 - q) * 16 + h];
    v.z = tbl[t5_bucket(kb + 2 - q) * 16 + h];
    v.w = tbl[t5_bucket(kb + 3 - q) * 16 + h];
  }
  ((float4*)outb)[((size_t)h * 2048 + q) * 512 + k4] = v;
}

// ---------------- fp16 MFMA GEMM (m97 pattern): 128x128 tile, BK=32 ----------------
template <bool F16OUT>
__global__ __launch_bounds__(256, 2) void k_gemm(const _Float16* __restrict__ A,
                                                 const _Float16* __restrict__ BT,
                                                 void* __restrict__ Cv, int K, int ldc) {
  __shared__ __align__(16) _Float16 As[128 * 32];
  __shared__ __align__(16) _Float16 Bs[128 * 32];
  const int tid = threadIdx.x;
  const int wave = tid >> 6, lane = tid & 63;
  const int l15 = lane & 15, quad = lane >> 4;
  const int m0 = blockIdx.y * 128, n0 = blockIdx.x * 128;
  const int wm = (wave >> 1) * 64, wn = (wave & 1) * 64;
  const int r0 = tid >> 2, c0 = (tid & 3) * 8;
  v4f acc[4][4] = {};
  for (int k0 = 0; k0 < K; k0 += 32) {
    __syncthreads();
    async_ld16(A + (size_t)(m0 + r0) * K + k0 + c0, (char*)As + (size_t)(wave * 64) * 16);
    async_ld16(A + (size_t)(m0 + 64 + r0) * K + k0 + c0,
               (char*)As + (size_t)(256 + wave * 64) * 16);
    async_ld16(BT + (size_t)(n0 + r0) * K + k0 + c0, (char*)Bs + (size_t)(wave * 64) * 16);
    async_ld16(BT + (size_t)(n0 + 64 + r0) * K + k0 + c0,
               (char*)Bs + (size_t)(256 + wave * 64) * 16);
    __syncthreads();
    half8 af[4], bf[4];
#pragma unroll
    for (int mt = 0; mt < 4; ++mt)
      af[mt] = *(const half8*)(As + (wm + mt * 16 + l15) * 32 + quad * 8);
#pragma unroll
    for (int nt = 0; nt < 4; ++nt)
      bf[nt] = *(const half8*)(Bs + (wn + nt * 16 + l15) * 32 + quad * 8);
#pragma unroll
    for (int mt = 0; mt < 4; ++mt)
#pragma unroll
      for (int nt = 0; nt < 4; ++nt)
        acc[mt][nt] = __builtin_amdgcn_mfma_f32_16x16x32_f16(af[mt], bf[nt], acc[mt][nt], 0, 0, 0);
  }
#pragma unroll
  for (int mt = 0; mt < 4; ++mt)
#pragma unroll
    for (int nt = 0; nt < 4; ++nt)
#pragma unroll
      for (int r = 0; r < 4; ++r) {
        int row = m0 + wm + mt * 16 + quad * 4 + r;
        int col = n0 + wn + nt * 16 + l15;
        if (F16OUT)
          ((_Float16*)Cv)[(size_t)row * ldc + col] = (_Float16)acc[mt][nt][r];
        else
          ((float*)Cv)[(size_t)row * ldc + col] = acc[mt][nt][r];
      }
}

// ---------------- output projection GEMM: 128x64 tile (2 blocks/CU for N=1024) ----------
__global__ __launch_bounds__(256, 2) void k_gemm_n64(const _Float16* __restrict__ A,
                                                     const _Float16* __restrict__ BT,
                                                     float* __restrict__ C, int K, int ldc) {
  __shared__ __align__(16) _Float16 As[128 * 32];
  __shared__ __align__(16) _Float16 Bs[64 * 32];
  const int tid = threadIdx.x;
  const int wave = tid >> 6, lane = tid & 63;
  const int l15 = lane & 15, quad = lane >> 4;
  const int m0 = blockIdx.y * 128, n0 = blockIdx.x * 64;
  const int wm = (wave >> 1) * 64, wn = (wave & 1) * 32;
  const int r0 = tid >> 2, c0 = (tid & 3) * 8;
  v4f acc[4][2] = {};
  for (int k0 = 0; k0 < K; k0 += 32) {
    __syncthreads();
    async_ld16(A + (size_t)(m0 + r0) * K + k0 + c0, (char*)As + (size_t)(wave * 64) * 16);
    async_ld16(A + (size_t)(m0 + 64 + r0) * K + k0 + c0,
               (char*)As + (size_t)(256 + wave * 64) * 16);
    async_ld16(BT + (size_t)(n0 + r0) * K + k0 + c0, (char*)Bs + (size_t)(wave * 64) * 16);
    __syncthreads();
    half8 af[4], bf[2];
#pragma unroll
    for (int mt = 0; mt < 4; ++mt)
      af[mt] = *(const half8*)(As + (wm + mt * 16 + l15) * 32 + quad * 8);
#pragma unroll
    for (int nt = 0; nt < 2; ++nt)
      bf[nt] = *(const half8*)(Bs + (wn + nt * 16 + l15) * 32 + quad * 8);
#pragma unroll
    for (int mt = 0; mt < 4; ++mt)
#pragma unroll
      for (int nt = 0; nt < 2; ++nt)
        acc[mt][nt] = __builtin_amdgcn_mfma_f32_16x16x32_f16(af[mt], bf[nt], acc[mt][nt], 0, 0, 0);
  }
#pragma unroll
  for (int mt = 0; mt < 4; ++mt)
#pragma unroll
    for (int nt = 0; nt < 2; ++nt)
#pragma unroll
      for (int r = 0; r < 4; ++r)
        C[(size_t)(m0 + wm + mt * 16 + quad * 4 + r) * ldc + n0 + wn + nt * 16 + l15] =
            acc[mt][nt][r];
}

// ---------------- fused flash attention, operand-swapped (q = N dim) ----------------
// grid (S/128, H, B); 4 waves; wave w owns q-rows q0 + w*32 .. +31 (two 16-col MFMA groups).
// S^T = K * Q^T  (lane l15 = one q; scores for 16 kv in-register, 4 consecutive kv per reg)
// O^T = V^T * P^T accumulated in C-layout (lane l15 = q, rows = d).
__global__ __launch_bounds__(256, 3) void k_attn(const _Float16* __restrict__ qkv,
                                                 const _Float16* __restrict__ vT,
                                                 const float* __restrict__ mask,
                                                 const float* __restrict__ rel,
                                                 _Float16* __restrict__ ctx) {
  constexpr int S = 2048, LD = 3072;
  __shared__ __align__(16) _Float16 Ks[64 * 72];    // [kv][d] pad->LD 72 (16B aligned rows)
  __shared__ __align__(16) _Float16 VT[64 * 72];    // [d][kv]
  __shared__ __align__(16) _Float16 Psh[128 * 72];  // [q][kv]
  __shared__ float btab[512];                       // bias vs delta in [-256,255]
  const int tid = threadIdx.x, wave = tid >> 6, lane = tid & 63;
  const int l15 = lane & 15, quad = lane >> 4;
  const int q0 = blockIdx.x * 128, h = blockIdx.y, b = blockIdx.z;

  for (int j = tid; j < 512; j += 256) btab[j] = rel[t5_bucket(j - 256) * 16 + h];
  const float c_past = rel[15 * 16 + h];  // q - k >= 91
  const float c_fut = rel[31 * 16 + h];   // k - q >= 91

  // Q fragments (B-operand: lane l15 = q, holds d = kc*32 + quad*8 + j)
  half8 bq[2][2];
#pragma unroll
  for (int qt = 0; qt < 2; ++qt) {
    const _Float16* qp = qkv + (size_t)(b * S + q0 + wave * 32 + qt * 16 + l15) * LD + h * 64;
    bq[qt][0] = *(const half8*)(qp + quad * 8);
    bq[qt][1] = *(const half8*)(qp + 32 + quad * 8);
  }
  v4f o[2][4] = {};
  float mrun[2] = {-INFINITY, -INFINITY};
  float lrun[2] = {0.f, 0.f};

  const int srow = tid >> 2, scol = (tid & 3) * 8;
  const _Float16* kg = qkv + (size_t)(b * S + srow) * LD + 1024 + h * 64 + scol;
  const _Float16* vg = vT + ((size_t)((b * 16 + h) * 64 + srow)) * S + scol;
  const float4* mkp = (const float4*)(mask + (size_t)b * S);

  for (int kv0 = 0; kv0 < S; kv0 += 64) {
    // global prefetch (latency overlaps barrier wait)
    half8 kr0 = *(const half8*)(kg + (size_t)kv0 * LD);
    half8 kr1 = *(const half8*)(kg + (size_t)kv0 * LD + 32);
    half8 vr0 = *(const half8*)(vg + kv0);
    half8 vr1 = *(const half8*)(vg + kv0 + 32);
    float4 mk[4];
#pragma unroll
    for (int mt = 0; mt < 4; ++mt) mk[mt] = mkp[(kv0 >> 2) + mt * 4 + quad];
    __syncthreads();  // prev-iter LDS reads done
    *(half8*)(Ks + srow * 72 + scol) = kr0;
    *(half8*)(Ks + srow * 72 + scol + 32) = kr1;
    *(half8*)(VT + srow * 72 + scol) = vr0;
    *(half8*)(VT + srow * 72 + scol + 32) = vr1;
    __syncthreads();  // staging visible

    // S^T tile: sc[qt][mt][r] = score(kv = kv0+mt*16+quad*4+r, q = q0+wave*32+qt*16+l15)
    v4f sc[2][4] = {};
#pragma unroll
    for (int kc = 0; kc < 2; ++kc)
#pragma unroll
      for (int mt = 0; mt < 4; ++mt) {
        half8 af = *(const half8*)(Ks + (mt * 16 + l15) * 72 + kc * 32 + quad * 8);
        sc[0][mt] = __builtin_amdgcn_mfma_f32_16x16x32_f16(af, bq[0][0 + kc], sc[0][mt], 0, 0, 0);
        sc[1][mt] = __builtin_amdgcn_mfma_f32_16x16x32_f16(af, bq[1][0 + kc], sc[1][mt], 0, 0, 0);
      }

    // bias + mask. Block-uniform tile classification: diff = kv0 - q0.
    const int diff = kv0 - q0;
    const bool mixed = (diff >= -153) && (diff <= 217);
    const float cf = (diff >= 218) ? c_fut : c_past;
    v4f cm[4];
#pragma unroll
    for (int mt = 0; mt < 4; ++mt) {
      cm[mt][0] = mk[mt].x; cm[mt][1] = mk[mt].y; cm[mt][2] = mk[mt].z; cm[mt][3] = mk[mt].w;
      if (!mixed) {
        cm[mt][0] += cf; cm[mt][1] += cf; cm[mt][2] += cf; cm[mt][3] += cf;
      }
    }
    if (mixed) {
#pragma unroll
      for (int qt = 0; qt < 2; ++qt) {
        const int qq = q0 + wave * 32 + qt * 16 + l15;
#pragma unroll
        for (int mt = 0; mt < 4; ++mt) {
          int base = kv0 + mt * 16 + quad * 4 - qq + 256;
#pragma unroll
          for (int r = 0; r < 4; ++r) sc[qt][mt][r] += btab[base + r] + cm[mt][r];
        }
      }
    } else {
#pragma unroll
      for (int qt = 0; qt < 2; ++qt)
#pragma unroll
        for (int mt = 0; mt < 4; ++mt)
#pragma unroll
          for (int r = 0; r < 4; ++r) sc[qt][mt][r] += cm[mt][r];
    }

    // online softmax per qt: one q per lane -> scalar state, 2 shuffles per reduction
#pragma unroll
    for (int qt = 0; qt < 2; ++qt) {
      v4f m4 = sc[qt][0];
#pragma unroll
      for (int r = 0; r < 4; ++r) {
        m4[r] = fmaxf(m4[r], sc[qt][1][r]);
        m4[r] = fmaxf(m4[r], sc[qt][2][r]);
        m4[r] = fmaxf(m4[r], sc[qt][3][r]);
      }
      float mx = fmaxf(fmaxf(m4[0], m4[1]), fmaxf(m4[2], m4[3]));
      mx = fmaxf(mx, __shfl_xor(mx, 16, 64));
      mx = fmaxf(mx, __shfl_xor(mx, 32, 64));
      float mnew = fmaxf(mrun[qt], mx);
      float alpha = __expf(mrun[qt] - mnew);
      mrun[qt] = mnew;
      v4f s4 = {};
#pragma unroll
      for (int mt = 0; mt < 4; ++mt)
#pragma unroll
        for (int r = 0; r < 4; ++r) {
          float p = __expf(sc[qt][mt][r] - mnew);
          sc[qt][mt][r] = p;
          s4[r] += p;
        }
      float rs = (s4[0] + s4[1]) + (s4[2] + s4[3]);
      rs += __shfl_xor(rs, 16, 64);
      rs += __shfl_xor(rs, 32, 64);
      lrun[qt] = lrun[qt] * alpha + rs;
#pragma unroll
      for (int dt = 0; dt < 4; ++dt)
#pragma unroll
        for (int r = 0; r < 4; ++r) o[qt][dt][r] *= alpha;
      // P write: 4 consecutive kv per lane -> packed b64
      const int prow = wave * 32 + qt * 16 + l15;
#pragma unroll
      for (int mt = 0; mt < 4; ++mt) {
        half4_t ph = {(_Float16)sc[qt][mt][0], (_Float16)sc[qt][mt][1],
                      (_Float16)sc[qt][mt][2], (_Float16)sc[qt][mt][3]};
        *(half4_t*)(Psh + prow * 72 + mt * 16 + quad * 4) = ph;
      }
    }
    __syncthreads();  // P visible

    // O^T += V^T * P^T
#pragma unroll
    for (int kc = 0; kc < 2; ++kc) {
      half8 bp0 = *(const half8*)(Psh + (wave * 32 + l15) * 72 + kc * 32 + quad * 8);
      half8 bp1 = *(const half8*)(Psh + (wave * 32 + 16 + l15) * 72 + kc * 32 + quad * 8);
#pragma unroll
      for (int dt = 0; dt < 4; ++dt) {
        half8 av = *(const half8*)(VT + (dt * 16 + l15) * 72 + kc * 32 + quad * 8);
        o[0][dt] = __builtin_amdgcn_mfma_f32_16x16x32_f16(av, bp0, o[0][dt], 0, 0, 0);
        o[1][dt] = __builtin_amdgcn_mfma_f32_16x16x32_f16(av, bp1, o[1][dt], 0, 0, 0);
      }
    }
  }
  // epilogue: ctx[token][h*64+d], d = dt*16 + quad*4 + r, token col = l15
#pragma unroll
  for (int qt = 0; qt < 2; ++qt) {
    float inv = 1.0f / lrun[qt];
    const size_t token = (size_t)(b * S + q0 + wave * 32 + qt * 16 + l15);
#pragma unroll
    for (int dt = 0; dt < 4; ++dt) {
      half4_t hv = {(_Float16)(o[qt][dt][0] * inv), (_Float16)(o[qt][dt][1] * inv),
                    (_Float16)(o[qt][dt][2] * inv), (_Float16)(o[qt][dt][3] * inv)};
      *(half4_t*)(ctx + token * 1024 + h * 64 + dt * 16 + quad * 4) = hv;
    }
  }
}

extern "C" void kernel_launch(void* const* d_in, const int* in_sizes, int n_in,
                              void* d_out, int out_size, void* d_ws, size_t ws_size,
                              hipStream_t stream) {
  const float* hs = (const float*)d_in[0];
  const float* mask = (const float*)d_in[1];
  const float* Wq = (const float*)d_in[2];
  const float* Wk = (const float*)d_in[3];
  const float* Wv = (const float*)d_in[4];
  const float* Wo = (const float*)d_in[5];
  const float* rel = (const float*)d_in[6];
  float* out = (float*)d_out;

  // workspace layout (56 MB)
  char* ws = (char*)d_ws;
  _Float16* hsF = (_Float16*)(ws);                 // [4096,1024]   8 MB
  _Float16* wqkvT = (_Float16*)(ws + (8u << 20));  // [3072,1024]   6 MB
  _Float16* woT = (_Float16*)(ws + (14u << 20));   // [1024,1024]   2 MB
  _Float16* qkv = (_Float16*)(ws + (16u << 20));   // [4096,3072]  24 MB
  _Float16* ctx = (_Float16*)(ws + (40u << 20));   // [4096,1024]   8 MB
  _Float16* vT = (_Float16*)(ws + (48u << 20));    // [2,16,64,2048] 8 MB

  k_cvt<<<4096, 256, 0, stream>>>(hs, hsF);
  k_wt<<<dim3(32, 32), dim3(32, 8), 0, stream>>>(Wq, wqkvT);
  k_wt<<<dim3(32, 32), dim3(32, 8), 0, stream>>>(Wk, wqkvT + (1u << 20));
  k_wt<<<dim3(32, 32), dim3(32, 8), 0, stream>>>(Wv, wqkvT + (2u << 20));
  k_wt<<<dim3(32, 32), dim3(32, 8), 0, stream>>>(Wo, woT);

  k_gemm<true><<<dim3(24, 32), 256, 0, stream>>>(hsF, wqkvT, qkv, 1024, 3072);
  k_vt<<<dim3(32, 16, 2), 256, 0, stream>>>(qkv, vT);
  k_bias<<<65536, 256, 0, stream>>>(rel, out + 4194304);
  k_attn<<<dim3(16, 16, 2), 256, 0, stream>>>(qkv, vT, mask, rel, ctx);
  k_gemm_n64<<<dim3(16, 32), 256, 0, stream>>>(ctx, woT, out, 1024, 1024);
}

// Round 3
// 436.899 us; speedup vs baseline: 1.2484x; 1.0550x over previous
//
#include <hip/hip_runtime.h>
#include <cstdint>

#define AS1 __attribute__((address_space(1)))
#define AS3 __attribute__((address_space(3)))

typedef _Float16 half8 __attribute__((ext_vector_type(8)));
typedef _Float16 half4_t __attribute__((ext_vector_type(4)));
typedef float v4f __attribute__((ext_vector_type(4)));

__device__ __forceinline__ void async_ld16(const void* g, void* l) {
  __builtin_amdgcn_global_load_lds((const AS1 uint32_t*)g, (AS3 uint32_t*)l, 16, 0, 0);
}

// T5 relative-position bucket for delta = k - q (bidirectional, 32 buckets, max_dist 128).
// Exact-boundary cases (n = 8,16,32,64) in integer arithmetic; n>=91 clamps; float path
// has >=0.015 margin in value space vs ~1e-6 fp32 error.
__device__ __forceinline__ int t5_bucket(int delta) {
  int n = -delta;  // n = q - k
  int ret = 0;
  if (n < 0) { ret = 16; n = -n; }
  if (n < 8) return n + ret;
  if (n >= 91) return 15 + ret;
  if ((n & (n - 1)) == 0) {
    int l = 31 - __clz(n);
    int v = 2 + 2 * l;
    return (v > 15 ? 15 : v) + ret;
  }
  int v = 8 + (int)(logf((float)n * 0.125f) * (8.0f / logf(16.0f)));
  return (v > 15 ? 15 : v) + ret;
}

// ---------------- fp32 -> fp16 convert (hidden states) ----------------
__global__ void k_cvt(const float* __restrict__ src, _Float16* __restrict__ dst) {
  int t = blockIdx.x * 256 + threadIdx.x;
  float4 f = ((const float4*)src)[t];
  half4_t h = {(_Float16)f.x, (_Float16)f.y, (_Float16)f.z, (_Float16)f.w};
  ((half4_t*)dst)[t] = h;
}

// ---------------- fp32 1024x1024 transpose -> fp16 (all 4 weights, z = which) ----------
__global__ void k_wt_all(const float* __restrict__ Wq, const float* __restrict__ Wk,
                         const float* __restrict__ Wv, const float* __restrict__ Wo,
                         _Float16* __restrict__ wqkvT, _Float16* __restrict__ woT) {
  __shared__ float tile[32][33];
  const int z = blockIdx.z;
  const float* src = (z == 0) ? Wq : (z == 1) ? Wk : (z == 2) ? Wv : Wo;
  _Float16* dst = (z < 3) ? (wqkvT + ((size_t)z << 20)) : woT;
  int tx = threadIdx.x, ty = threadIdx.y;
  int bx = blockIdx.x * 32, by = blockIdx.y * 32;
#pragma unroll
  for (int i = 0; i < 32; i += 8)
    tile[ty + i][tx] = src[(size_t)(by + ty + i) * 1024 + bx + tx];
  __syncthreads();
#pragma unroll
  for (int i = 0; i < 32; i += 8)
    dst[(size_t)(bx + ty + i) * 1024 + by + tx] = (_Float16)tile[tx][ty + i];
}

// ---------------- fp16 MFMA GEMM (m97 pattern): 128x128 tile, BK=32 ----------------
// F16OUT path: V-range blocks (n0 >= 2048) store transposed into vT instead of C.
template <bool F16OUT>
__global__ __launch_bounds__(256, 2) void k_gemm(const _Float16* __restrict__ A,
                                                 const _Float16* __restrict__ BT,
                                                 void* __restrict__ Cv,
                                                 _Float16* __restrict__ vT, int K, int ldc) {
  __shared__ __align__(16) _Float16 As[128 * 32];
  __shared__ __align__(16) _Float16 Bs[128 * 32];
  const int tid = threadIdx.x;
  const int wave = tid >> 6, lane = tid & 63;
  const int l15 = lane & 15, quad = lane >> 4;
  const int m0 = blockIdx.y * 128, n0 = blockIdx.x * 128;
  const int wm = (wave >> 1) * 64, wn = (wave & 1) * 64;
  const int r0 = tid >> 2, c0 = (tid & 3) * 8;
  v4f acc[4][4] = {};
  for (int k0 = 0; k0 < K; k0 += 32) {
    __syncthreads();
    async_ld16(A + (size_t)(m0 + r0) * K + k0 + c0, (char*)As + (size_t)(wave * 64) * 16);
    async_ld16(A + (size_t)(m0 + 64 + r0) * K + k0 + c0,
               (char*)As + (size_t)(256 + wave * 64) * 16);
    async_ld16(BT + (size_t)(n0 + r0) * K + k0 + c0, (char*)Bs + (size_t)(wave * 64) * 16);
    async_ld16(BT + (size_t)(n0 + 64 + r0) * K + k0 + c0,
               (char*)Bs + (size_t)(256 + wave * 64) * 16);
    __syncthreads();
    half8 af[4], bf[4];
#pragma unroll
    for (int mt = 0; mt < 4; ++mt)
      af[mt] = *(const half8*)(As + (wm + mt * 16 + l15) * 32 + quad * 8);
#pragma unroll
    for (int nt = 0; nt < 4; ++nt)
      bf[nt] = *(const half8*)(Bs + (wn + nt * 16 + l15) * 32 + quad * 8);
#pragma unroll
    for (int mt = 0; mt < 4; ++mt)
#pragma unroll
      for (int nt = 0; nt < 4; ++nt)
        acc[mt][nt] = __builtin_amdgcn_mfma_f32_16x16x32_f16(af[mt], bf[nt], acc[mt][nt], 0, 0, 0);
  }
  if (F16OUT && n0 >= 2048) {
    // V block: write vT[((b*16+h)*64+d)][s], 4 consecutive s per lane -> b64 stores
#pragma unroll
    for (int mt = 0; mt < 4; ++mt)
#pragma unroll
      for (int nt = 0; nt < 4; ++nt) {
        int col = n0 + wn + nt * 16 + l15 - 2048;  // h*64 + d
        int row0 = m0 + wm + mt * 16 + quad * 4;   // token
        int bb = row0 >> 11, s0 = row0 & 2047;
        half4_t hv = {(_Float16)acc[mt][nt][0], (_Float16)acc[mt][nt][1],
                      (_Float16)acc[mt][nt][2], (_Float16)acc[mt][nt][3]};
        *(half4_t*)(vT + ((size_t)bb * 1024 + col) * 2048 + s0) = hv;
      }
    return;
  }
#pragma unroll
  for (int mt = 0; mt < 4; ++mt)
#pragma unroll
    for (int nt = 0; nt < 4; ++nt)
#pragma unroll
      for (int r = 0; r < 4; ++r) {
        int row = m0 + wm + mt * 16 + quad * 4 + r;
        int col = n0 + wn + nt * 16 + l15;
        if (F16OUT)
          ((_Float16*)Cv)[(size_t)row * ldc + col] = (_Float16)acc[mt][nt][r];
        else
          ((float*)Cv)[(size_t)row * ldc + col] = acc[mt][nt][r];
      }
}

// ---------------- output projection GEMM: 128x64 tile ----------------
__global__ __launch_bounds__(256, 2) void k_gemm_n64(const _Float16* __restrict__ A,
                                                     const _Float16* __restrict__ BT,
                                                     float* __restrict__ C, int K, int ldc) {
  __shared__ __align__(16) _Float16 As[128 * 32];
  __shared__ __align__(16) _Float16 Bs[64 * 32];
  const int tid = threadIdx.x;
  const int wave = tid >> 6, lane = tid & 63;
  const int l15 = lane & 15, quad = lane >> 4;
  const int m0 = blockIdx.y * 128, n0 = blockIdx.x * 64;
  const int wm = (wave >> 1) * 64, wn = (wave & 1) * 32;
  const int r0 = tid >> 2, c0 = (tid & 3) * 8;
  v4f acc[4][2] = {};
  for (int k0 = 0; k0 < K; k0 += 32) {
    __syncthreads();
    async_ld16(A + (size_t)(m0 + r0) * K + k0 + c0, (char*)As + (size_t)(wave * 64) * 16);
    async_ld16(A + (size_t)(m0 + 64 + r0) * K + k0 + c0,
               (char*)As + (size_t)(256 + wave * 64) * 16);
    async_ld16(BT + (size_t)(n0 + r0) * K + k0 + c0, (char*)Bs + (size_t)(wave * 64) * 16);
    __syncthreads();
    half8 af[4], bf[2];
#pragma unroll
    for (int mt = 0; mt < 4; ++mt)
      af[mt] = *(const half8*)(As + (wm + mt * 16 + l15) * 32 + quad * 8);
#pragma unroll
    for (int nt = 0; nt < 2; ++nt)
      bf[nt] = *(const half8*)(Bs + (wn + nt * 16 + l15) * 32 + quad * 8);
#pragma unroll
    for (int mt = 0; mt < 4; ++mt)
#pragma unroll
      for (int nt = 0; nt < 2; ++nt)
        acc[mt][nt] = __builtin_amdgcn_mfma_f32_16x16x32_f16(af[mt], bf[nt], acc[mt][nt], 0, 0, 0);
  }
#pragma unroll
  for (int mt = 0; mt < 4; ++mt)
#pragma unroll
    for (int nt = 0; nt < 2; ++nt)
#pragma unroll
      for (int r = 0; r < 4; ++r)
        C[(size_t)(m0 + wm + mt * 16 + quad * 4 + r) * ldc + n0 + wn + nt * 16 + l15] =
            acc[mt][nt][r];
}

// ---------------- fused flash attention + position-bias writer ----------------
// grid (24, 16, 2): x<16 attn q-tile (q0=x*128); x in [16,24) bias writer blocks
// (each covers 1/8 of (h, q-half b) = 256 iters of coalesced float4 stores).
__global__ __launch_bounds__(256, 3) void k_attn_bias(const _Float16* __restrict__ qkv,
                                                      const _Float16* __restrict__ vT,
                                                      const float* __restrict__ mask,
                                                      const float* __restrict__ rel,
                                                      _Float16* __restrict__ ctx,
                                                      float* __restrict__ outb) {
  constexpr int S = 2048, LD = 3072;
  __shared__ __align__(16) _Float16 Ks[64 * 72];    // [kv][d] pad->LD 72
  __shared__ __align__(16) _Float16 VT[64 * 72];    // [d][kv]
  __shared__ __align__(16) _Float16 Psh[128 * 72];  // [q][kv]
  __shared__ float btab[512];                       // bias vs delta in [-256,255]
  const int tid = threadIdx.x, wave = tid >> 6, lane = tid & 63;
  const int l15 = lane & 15, quad = lane >> 4;
  const int h = blockIdx.y, b = blockIdx.z;

  for (int j = tid; j < 512; j += 256) btab[j] = rel[t5_bucket(j - 256) * 16 + h];
  const float c_past = rel[15 * 16 + h];  // q - k >= 91
  const float c_fut = rel[31 * 16 + h];   // k - q >= 91
  __syncthreads();

  if (blockIdx.x >= 16) {
    // ---- bias writer: out[h][q][k], q in [b*1024, b*1024+1024), this block's 1/8 slice
    const int blk = blockIdx.x - 16;  // 0..7
    float4* op = (float4*)outb + (size_t)h * 2048 * 512;
#pragma unroll 4
    for (int i = 0; i < 256; ++i) {
      int idx = blk * 65536 + i * 256 + tid;  // within (h, half): 1024 q x 512 k4
      int k4 = idx & 511;
      int q = b * 1024 + (idx >> 9);
      int kb = k4 * 4;
      float4 v;
      if (kb - q >= 91) {
        v = make_float4(c_fut, c_fut, c_fut, c_fut);
      } else if (q - kb - 3 >= 91) {
        v = make_float4(c_past, c_past, c_past, c_past);
      } else {
        v.x = btab[kb + 0 - q + 256];
        v.y = btab[kb + 1 - q + 256];
        v.z = btab[kb + 2 - q + 256];
        v.w = btab[kb + 3 - q + 256];
      }
      op[(size_t)q * 512 + k4] = v;
    }
    return;
  }

  // ---- attention path (operand-swapped flash, q = N dim) ----
  const int q0 = blockIdx.x * 128;

  half8 bq[2][2];
#pragma unroll
  for (int qt = 0; qt < 2; ++qt) {
    const _Float16* qp = qkv + (size_t)(b * S + q0 + wave * 32 + qt * 16 + l15) * LD + h * 64;
    bq[qt][0] = *(const half8*)(qp + quad * 8);
    bq[qt][1] = *(const half8*)(qp + 32 + quad * 8);
  }
  v4f o[2][4] = {};
  float mrun[2] = {-INFINITY, -INFINITY};
  float lrun[2] = {0.f, 0.f};

  const int srow = tid >> 2, scol = (tid & 3) * 8;
  const _Float16* kg = qkv + (size_t)(b * S + srow) * LD + 1024 + h * 64 + scol;
  const _Float16* vg = vT + ((size_t)((b * 16 + h) * 64 + srow)) * S + scol;
  const float4* mkp = (const float4*)(mask + (size_t)b * S);

  for (int kv0 = 0; kv0 < S; kv0 += 64) {
    half8 kr0 = *(const half8*)(kg + (size_t)kv0 * LD);
    half8 kr1 = *(const half8*)(kg + (size_t)kv0 * LD + 32);
    half8 vr0 = *(const half8*)(vg + kv0);
    half8 vr1 = *(const half8*)(vg + kv0 + 32);
    float4 mk[4];
#pragma unroll
    for (int mt = 0; mt < 4; ++mt) mk[mt] = mkp[(kv0 >> 2) + mt * 4 + quad];
    __syncthreads();
    *(half8*)(Ks + srow * 72 + scol) = kr0;
    *(half8*)(Ks + srow * 72 + scol + 32) = kr1;
    *(half8*)(VT + srow * 72 + scol) = vr0;
    *(half8*)(VT + srow * 72 + scol + 32) = vr1;
    __syncthreads();

    v4f sc[2][4] = {};
#pragma unroll
    for (int kc = 0; kc < 2; ++kc)
#pragma unroll
      for (int mt = 0; mt < 4; ++mt) {
        half8 af = *(const half8*)(Ks + (mt * 16 + l15) * 72 + kc * 32 + quad * 8);
        sc[0][mt] = __builtin_amdgcn_mfma_f32_16x16x32_f16(af, bq[0][kc], sc[0][mt], 0, 0, 0);
        sc[1][mt] = __builtin_amdgcn_mfma_f32_16x16x32_f16(af, bq[1][kc], sc[1][mt], 0, 0, 0);
      }

    const int diff = kv0 - q0;
    const bool mixed = (diff >= -153) && (diff <= 217);
    const float cf = (diff >= 218) ? c_fut : c_past;
    v4f cm[4];
#pragma unroll
    for (int mt = 0; mt < 4; ++mt) {
      cm[mt][0] = mk[mt].x; cm[mt][1] = mk[mt].y; cm[mt][2] = mk[mt].z; cm[mt][3] = mk[mt].w;
      if (!mixed) {
        cm[mt][0] += cf; cm[mt][1] += cf; cm[mt][2] += cf; cm[mt][3] += cf;
      }
    }
    if (mixed) {
#pragma unroll
      for (int qt = 0; qt < 2; ++qt) {
        const int qq = q0 + wave * 32 + qt * 16 + l15;
#pragma unroll
        for (int mt = 0; mt < 4; ++mt) {
          int base = kv0 + mt * 16 + quad * 4 - qq + 256;
#pragma unroll
          for (int r = 0; r < 4; ++r) sc[qt][mt][r] += btab[base + r] + cm[mt][r];
        }
      }
    } else {
#pragma unroll
      for (int qt = 0; qt < 2; ++qt)
#pragma unroll
        for (int mt = 0; mt < 4; ++mt)
#pragma unroll
          for (int r = 0; r < 4; ++r) sc[qt][mt][r] += cm[mt][r];
    }

#pragma unroll
    for (int qt = 0; qt < 2; ++qt) {
      v4f m4 = sc[qt][0];
#pragma unroll
      for (int r = 0; r < 4; ++r) {
        m4[r] = fmaxf(m4[r], sc[qt][1][r]);
        m4[r] = fmaxf(m4[r], sc[qt][2][r]);
        m4[r] = fmaxf(m4[r], sc[qt][3][r]);
      }
      float mx = fmaxf(fmaxf(m4[0], m4[1]), fmaxf(m4[2], m4[3]));
      mx = fmaxf(mx, __shfl_xor(mx, 16, 64));
      mx = fmaxf(mx, __shfl_xor(mx, 32, 64));
      float mnew = fmaxf(mrun[qt], mx);
      float alpha = __expf(mrun[qt] - mnew);
      mrun[qt] = mnew;
      v4f s4 = {};
#pragma unroll
      for (int mt = 0; mt < 4; ++mt)
#pragma unroll
        for (int r = 0; r < 4; ++r) {
          float p = __expf(sc[qt][mt][r] - mnew);
          sc[qt][mt][r] = p;
          s4[r] += p;
        }
      float rs = (s4[0] + s4[1]) + (s4[2] + s4[3]);
      rs += __shfl_xor(rs, 16, 64);
      rs += __shfl_xor(rs, 32, 64);
      lrun[qt] = lrun[qt] * alpha + rs;
#pragma unroll
      for (int dt = 0; dt < 4; ++dt)
#pragma unroll
        for (int r = 0; r < 4; ++r) o[qt][dt][r] *= alpha;
      const int prow = wave * 32 + qt * 16 + l15;
#pragma unroll
      for (int mt = 0; mt < 4; ++mt) {
        half4_t ph = {(_Float16)sc[qt][mt][0], (_Float16)sc[qt][mt][1],
                      (_Float16)sc[qt][mt][2], (_Float16)sc[qt][mt][3]};
        *(half4_t*)(Psh + prow * 72 + mt * 16 + quad * 4) = ph;
      }
    }
    __syncthreads();

#pragma unroll
    for (int kc = 0; kc < 2; ++kc) {
      half8 bp0 = *(const half8*)(Psh + (wave * 32 + l15) * 72 + kc * 32 + quad * 8);
      half8 bp1 = *(const half8*)(Psh + (wave * 32 + 16 + l15) * 72 + kc * 32 + quad * 8);
#pragma unroll
      for (int dt = 0; dt < 4; ++dt) {
        half8 av = *(const half8*)(VT + (dt * 16 + l15) * 72 + kc * 32 + quad * 8);
        o[0][dt] = __builtin_amdgcn_mfma_f32_16x16x32_f16(av, bp0, o[0][dt], 0, 0, 0);
        o[1][dt] = __builtin_amdgcn_mfma_f32_16x16x32_f16(av, bp1, o[1][dt], 0, 0, 0);
      }
    }
  }
#pragma unroll
  for (int qt = 0; qt < 2; ++qt) {
    float inv = 1.0f / lrun[qt];
    const size_t token = (size_t)(b * S + q0 + wave * 32 + qt * 16 + l15);
#pragma unroll
    for (int dt = 0; dt < 4; ++dt) {
      half4_t hv = {(_Float16)(o[qt][dt][0] * inv), (_Float16)(o[qt][dt][1] * inv),
                    (_Float16)(o[qt][dt][2] * inv), (_Float16)(o[qt][dt][3] * inv)};
      *(half4_t*)(ctx + token * 1024 + h * 64 + dt * 16 + quad * 4) = hv;
    }
  }
}

extern "C" void kernel_launch(void* const* d_in, const int* in_sizes, int n_in,
                              void* d_out, int out_size, void* d_ws, size_t ws_size,
                              hipStream_t stream) {
  const float* hs = (const float*)d_in[0];
  const float* mask = (const float*)d_in[1];
  const float* Wq = (const float*)d_in[2];
  const float* Wk = (const float*)d_in[3];
  const float* Wv = (const float*)d_in[4];
  const float* Wo = (const float*)d_in[5];
  const float* rel = (const float*)d_in[6];
  float* out = (float*)d_out;

  // workspace layout (56 MB)
  char* ws = (char*)d_ws;
  _Float16* hsF = (_Float16*)(ws);                 // [4096,1024]   8 MB
  _Float16* wqkvT = (_Float16*)(ws + (8u << 20));  // [3072,1024]   6 MB
  _Float16* woT = (_Float16*)(ws + (14u << 20));   // [1024,1024]   2 MB
  _Float16* qkv = (_Float16*)(ws + (16u << 20));   // [4096,3072]  24 MB (V-part unused)
  _Float16* ctx = (_Float16*)(ws + (40u << 20));   // [4096,1024]   8 MB
  _Float16* vT = (_Float16*)(ws + (48u << 20));    // [2,16,64,2048] 8 MB

  k_cvt<<<4096, 256, 0, stream>>>(hs, hsF);
  k_wt_all<<<dim3(32, 32, 4), dim3(32, 8), 0, stream>>>(Wq, Wk, Wv, Wo, wqkvT, woT);

  // QKV projection; V-range blocks write vT directly (transposed epilogue)
  k_gemm<true><<<dim3(24, 32), 256, 0, stream>>>(hsF, wqkvT, qkv, vT, 1024, 3072);
  // fused attention + position-bias writer
  k_attn_bias<<<dim3(24, 16, 2), 256, 0, stream>>>(qkv, vT, mask, rel, ctx, out + 4194304);
  // output projection
  k_gemm_n64<<<dim3(16, 32), 256, 0, stream>>>(ctx, woT, out, 1024, 1024);
}